// Round 1
// baseline (388.294 us; speedup 1.0000x reference)
//
#include <hip/hip_runtime.h>
#include <hip/hip_bf16.h>
#include <stdint.h>

typedef __attribute__((ext_vector_type(8))) short bf16x8;
typedef __attribute__((ext_vector_type(4))) float f32x4;

#define DEVI static __device__ __forceinline__

// Problem sizes (fixed)
static constexpr int B_SZ = 4096, N_SZ = 128, H_SZ = 128, W_SZ = 64;

// ws layout (bytes), all 16B aligned
static constexpr size_t OFF_W1 = 0;                      // 128 * 128*128 bf16 = 4 MB (swizzled [n][kcol][h])
static constexpr size_t OFF_W2 = OFF_W1 + 4194304;       // 128 * 64*128 bf16 = 2 MB (swizzled [n][w][k])
static constexpr size_t OFF_F1 = OFF_W2 + 2097152;       // 128*128 bf16 = 32 KB (swizzled [j][h])
static constexpr size_t OFF_F2 = OFF_F1 + 32768;         // 384*128 bf16 = 96 KB (swizzled [o][j])
static constexpr size_t OFF_H  = OFF_F2 + 98304;         // 4096*128 bf16 = 1 MB (per-128-row tile, swizzled)

DEVI unsigned short f2bf(float f) {
  union { __hip_bfloat16 b; unsigned short u; } cv;
  cv.b = __float2bfloat16(f);
  return cv.u;
}

// Read one MFMA fragment (8 contiguous bf16 along k) from a swizzled LDS tile.
// Tile layout: row stride 256B; 16B slot s stored at (s ^ (row&7)).
DEVI bf16x8 frag_ld(const unsigned char* base, int row, int kslot) {
  return *reinterpret_cast<const bf16x8*>(base + row * 256 + (((kslot ^ (row & 7)) << 4)));
}

// Stage an nrows x 128 fp32 tile (row stride in elems) into swizzled bf16 LDS.
DEVI void stage_f32_tile(const float* src, int row_stride, unsigned char* dst, int tid, int nrows) {
  for (int t = tid; t < nrows * 16; t += 256) {
    int row = t >> 4, s = t & 15;
    const float* p = src + (size_t)row * row_stride + s * 8;
    union { unsigned short u[8]; uint4 v; } pk;
#pragma unroll
    for (int j = 0; j < 8; ++j) pk.u[j] = f2bf(p[j]);
    *reinterpret_cast<uint4*>(dst + row * 256 + ((s ^ (row & 7)) << 4)) = pk.v;
  }
}

// ---------------- prep: convert+transpose weights into ws (pre-swizzled bf16) ----------------
__global__ __launch_bounds__(256) void prep_kernel(const float* __restrict__ rw1,
                                                   const float* __restrict__ rw2,
                                                   const float* __restrict__ fc1w,
                                                   const float* __restrict__ fc2w,
                                                   unsigned char* __restrict__ ws) {
  const int T_W1 = 128 * 128 * 16;  // (n,s,kcol): W1s[n][kcol][h=s*8+j] = rw1[n][h][kcol]
  const int T_W2 = 128 * 64 * 16;   // (n,s,w):    W2s[n][w][k=s*8+j]    = rw2[n][k][w]
  const int T_F1 = 128 * 16;        // (o,s):      F1s[o][h]             = fc1w[o][h]
  const int T_F2 = 384 * 16;
  int id = blockIdx.x * 256 + threadIdx.x;
  if (id < T_W1) {
    int kcol = id & 127, rest = id >> 7;
    int s = rest & 15, n = rest >> 4;
    const float* src = rw1 + (size_t)n * 16384 + (size_t)(s * 8) * 128 + kcol;
    union { unsigned short u[8]; uint4 v; } pk;
#pragma unroll
    for (int j = 0; j < 8; ++j) pk.u[j] = f2bf(src[(size_t)j * 128]);
    size_t dst = OFF_W1 + ((size_t)n * 128 + kcol) * 256 + (size_t)((s ^ (kcol & 7)) << 4);
    *reinterpret_cast<uint4*>(ws + dst) = pk.v;
    return;
  }
  id -= T_W1;
  if (id < T_W2) {
    int w = id & 63, rest = id >> 6;
    int s = rest & 15, n = rest >> 4;
    const float* src = rw2 + (size_t)n * 8192 + (size_t)(s * 8) * 64 + w;
    union { unsigned short u[8]; uint4 v; } pk;
#pragma unroll
    for (int j = 0; j < 8; ++j) pk.u[j] = f2bf(src[(size_t)j * 64]);
    size_t dst = OFF_W2 + ((size_t)n * 64 + w) * 256 + (size_t)((s ^ (w & 7)) << 4);
    *reinterpret_cast<uint4*>(ws + dst) = pk.v;
    return;
  }
  id -= T_W2;
  if (id < T_F1) {
    int s = id & 15, o = id >> 4;
    const float* src = fc1w + (size_t)o * 128 + s * 8;
    union { unsigned short u[8]; uint4 v; } pk;
#pragma unroll
    for (int j = 0; j < 8; ++j) pk.u[j] = f2bf(src[j]);
    *reinterpret_cast<uint4*>(ws + OFF_F1 + (size_t)o * 256 + ((s ^ (o & 7)) << 4)) = pk.v;
    return;
  }
  id -= T_F1;
  if (id < T_F2) {
    int s = id & 15, o = id >> 4;
    const float* src = fc2w + (size_t)o * 128 + s * 8;
    union { unsigned short u[8]; uint4 v; } pk;
#pragma unroll
    for (int j = 0; j < 8; ++j) pk.u[j] = f2bf(src[j]);
    *reinterpret_cast<uint4*>(ws + OFF_F2 + (size_t)o * 256 + ((s ^ (o & 7)) << 4)) = pk.v;
  }
}

// ---------------- recon: per-node fused MLP (GEMM1+relu -> GEMM2), MFMA bf16 ----------------
__global__ __launch_bounds__(256) void recon_kernel(const float* __restrict__ se,
                                                    const float* __restrict__ rb1,
                                                    const float* __restrict__ rb2,
                                                    const unsigned char* __restrict__ ws,
                                                    float* __restrict__ out3) {
  __shared__ unsigned char sA[32768];   // SE tile (bf16, swizzled), later reused for hn
  __shared__ unsigned char sB1[32768];  // W1s[n]
  __shared__ unsigned char sB2[16384];  // W2s[n]

  const int tid = threadIdx.x;
  const int bt = blockIdx.x;   // 0..31 batch tiles of 128
  const int n = blockIdx.y;    // 0..127 node
  const int b0 = bt * 128;

  // stage weights (already bf16+swizzled in ws): plain linear copies
  {
    const uint4* w1p = reinterpret_cast<const uint4*>(ws + OFF_W1 + (size_t)n * 32768);
    uint4* d1 = reinterpret_cast<uint4*>(sB1);
    for (int c = tid; c < 2048; c += 256) d1[c] = w1p[c];
    const uint4* w2p = reinterpret_cast<const uint4*>(ws + OFF_W2 + (size_t)n * 16384);
    uint4* d2 = reinterpret_cast<uint4*>(sB2);
    for (int c = tid; c < 1024; c += 256) d2[c] = w2p[c];
  }
  // stage SE tile: rows (b0+r), node n ; row stride = N*H
  stage_f32_tile(se + ((size_t)b0 * 128 + n) * 128, 128 * 128, sA, tid, 128);
  __syncthreads();

  const int wave = tid >> 6, lane = tid & 63;
  const int wm = wave >> 1, wn = wave & 1;
  const int lr = lane & 15, lk = lane >> 4;

  // GEMM1: hn = relu(SE @ W1 + b1), 128x128x128; waves 2x2, each 64x64
  f32x4 acc[4][4] = {};
#pragma unroll
  for (int kk = 0; kk < 4; ++kk) {
    bf16x8 af[4], bfv[4];
#pragma unroll
    for (int m = 0; m < 4; ++m) af[m] = frag_ld(sA, wm * 64 + m * 16 + lr, kk * 4 + lk);
#pragma unroll
    for (int q = 0; q < 4; ++q) bfv[q] = frag_ld(sB1, wn * 64 + q * 16 + lr, kk * 4 + lk);
#pragma unroll
    for (int m = 0; m < 4; ++m)
#pragma unroll
      for (int q = 0; q < 4; ++q)
        acc[m][q] = __builtin_amdgcn_mfma_f32_16x16x32_bf16(af[m], bfv[q], acc[m][q], 0, 0, 0);
  }
  __syncthreads();  // everyone done reading sA

  // epilogue1: relu(acc + b1) -> bf16 into sA (swizzled [row][k])
  const float* b1p = rb1 + (size_t)n * 128;
#pragma unroll
  for (int q = 0; q < 4; ++q) {
    int c = wn * 64 + q * 16 + lr;
    float bias = b1p[c];
#pragma unroll
    for (int m = 0; m < 4; ++m) {
#pragma unroll
      for (int j = 0; j < 4; ++j) {
        int r = wm * 64 + m * 16 + lk * 4 + j;
        float v = acc[m][q][j] + bias;
        v = v > 0.f ? v : 0.f;
        *reinterpret_cast<unsigned short*>(sA + r * 256 + ((c * 2) ^ ((r & 7) << 4))) = f2bf(v);
      }
    }
  }
  __syncthreads();

  // GEMM2: recon = hn @ W2 + b2, 128x64x128; waves 2x2, each 64x32
  f32x4 acc2[4][2] = {};
#pragma unroll
  for (int kk = 0; kk < 4; ++kk) {
    bf16x8 af[4], bfv[2];
#pragma unroll
    for (int m = 0; m < 4; ++m) af[m] = frag_ld(sA, wm * 64 + m * 16 + lr, kk * 4 + lk);
#pragma unroll
    for (int q = 0; q < 2; ++q) bfv[q] = frag_ld(sB2, wn * 32 + q * 16 + lr, kk * 4 + lk);
#pragma unroll
    for (int m = 0; m < 4; ++m)
#pragma unroll
      for (int q = 0; q < 2; ++q)
        acc2[m][q] = __builtin_amdgcn_mfma_f32_16x16x32_bf16(af[m], bfv[q], acc2[m][q], 0, 0, 0);
  }

  // epilogue2: out3[b][w][n] (scattered fp32 stores, stride N)
  const float* b2p = rb2 + (size_t)n * 64;
#pragma unroll
  for (int q = 0; q < 2; ++q) {
    int w = wn * 32 + q * 16 + lr;
    float bias = b2p[w];
#pragma unroll
    for (int m = 0; m < 4; ++m) {
#pragma unroll
      for (int j = 0; j < 4; ++j) {
        int b = b0 + wm * 64 + m * 16 + lk * 4 + j;
        out3[(size_t)b * 8192 + (size_t)w * 128 + n] = acc2[m][q][j] + bias;
      }
    }
  }
}

// ---------------- forecast stage 1: h = relu(emb @ fc1^T + b1) -> ws (bf16, tile-swizzled) ----------------
__global__ __launch_bounds__(256) void f1_kernel(const float* __restrict__ emb,
                                                 const float* __restrict__ fc1b,
                                                 const unsigned char* __restrict__ ws,
                                                 unsigned char* __restrict__ hsw) {
  __shared__ unsigned char sA[32768];
  __shared__ unsigned char sB[32768];
  const int tid = threadIdx.x;
  const int bt = blockIdx.x;
  const int b0 = bt * 128;
  {
    const uint4* wp = reinterpret_cast<const uint4*>(ws + OFF_F1);
    uint4* d = reinterpret_cast<uint4*>(sB);
    for (int c = tid; c < 2048; c += 256) d[c] = wp[c];
  }
  stage_f32_tile(emb + (size_t)b0 * 128, 128, sA, tid, 128);
  __syncthreads();

  const int wave = tid >> 6, lane = tid & 63;
  const int wm = wave >> 1, wn = wave & 1;
  const int lr = lane & 15, lk = lane >> 4;

  f32x4 acc[4][4] = {};
#pragma unroll
  for (int kk = 0; kk < 4; ++kk) {
    bf16x8 af[4], bfv[4];
#pragma unroll
    for (int m = 0; m < 4; ++m) af[m] = frag_ld(sA, wm * 64 + m * 16 + lr, kk * 4 + lk);
#pragma unroll
    for (int q = 0; q < 4; ++q) bfv[q] = frag_ld(sB, wn * 64 + q * 16 + lr, kk * 4 + lk);
#pragma unroll
    for (int m = 0; m < 4; ++m)
#pragma unroll
      for (int q = 0; q < 4; ++q)
        acc[m][q] = __builtin_amdgcn_mfma_f32_16x16x32_bf16(af[m], bfv[q], acc[m][q], 0, 0, 0);
  }

  unsigned char* tile = hsw + (size_t)bt * 32768;
#pragma unroll
  for (int q = 0; q < 4; ++q) {
    int c = wn * 64 + q * 16 + lr;
    float bias = fc1b[c];
#pragma unroll
    for (int m = 0; m < 4; ++m) {
#pragma unroll
      for (int j = 0; j < 4; ++j) {
        int r = wm * 64 + m * 16 + lk * 4 + j;
        float v = acc[m][q][j] + bias;
        v = v > 0.f ? v : 0.f;
        *reinterpret_cast<unsigned short*>(tile + r * 256 + ((c * 2) ^ ((r & 7) << 4))) = f2bf(v);
      }
    }
  }
}

// ---------------- forecast stage 2: forecast = h @ fc2^T + b2 ----------------
__global__ __launch_bounds__(256) void f2_kernel(const unsigned char* __restrict__ hsw,
                                                 const unsigned char* __restrict__ f2s,
                                                 const float* __restrict__ fc2b,
                                                 float* __restrict__ out2) {
  __shared__ unsigned char sA[32768];
  __shared__ unsigned char sB[32768];
  const int tid = threadIdx.x;
  const int bt = blockIdx.x;      // 0..31
  const int ch = blockIdx.y;      // 0..2 (chunks of 128 output cols)
  const int b0 = bt * 128;
  {
    const uint4* ap = reinterpret_cast<const uint4*>(hsw + (size_t)bt * 32768);
    uint4* da = reinterpret_cast<uint4*>(sA);
    for (int c = tid; c < 2048; c += 256) da[c] = ap[c];
    const uint4* bp = reinterpret_cast<const uint4*>(f2s + (size_t)ch * 32768);
    uint4* db = reinterpret_cast<uint4*>(sB);
    for (int c = tid; c < 2048; c += 256) db[c] = bp[c];
  }
  __syncthreads();

  const int wave = tid >> 6, lane = tid & 63;
  const int wm = wave >> 1, wn = wave & 1;
  const int lr = lane & 15, lk = lane >> 4;

  f32x4 acc[4][4] = {};
#pragma unroll
  for (int kk = 0; kk < 4; ++kk) {
    bf16x8 af[4], bfv[4];
#pragma unroll
    for (int m = 0; m < 4; ++m) af[m] = frag_ld(sA, wm * 64 + m * 16 + lr, kk * 4 + lk);
#pragma unroll
    for (int q = 0; q < 4; ++q) bfv[q] = frag_ld(sB, wn * 64 + q * 16 + lr, kk * 4 + lk);
#pragma unroll
    for (int m = 0; m < 4; ++m)
#pragma unroll
      for (int q = 0; q < 4; ++q)
        acc[m][q] = __builtin_amdgcn_mfma_f32_16x16x32_bf16(af[m], bfv[q], acc[m][q], 0, 0, 0);
  }

#pragma unroll
  for (int q = 0; q < 4; ++q) {
    int o = ch * 128 + wn * 64 + q * 16 + lr;
    float bias = fc2b[o];
#pragma unroll
    for (int m = 0; m < 4; ++m) {
#pragma unroll
      for (int j = 0; j < 4; ++j) {
        int r = wm * 64 + m * 16 + lk * 4 + j;
        out2[(size_t)(b0 + r) * 384 + o] = acc[m][q][j] + bias;
      }
    }
  }
}

extern "C" void kernel_launch(void* const* d_in, const int* in_sizes, int n_in,
                              void* d_out, int out_size, void* d_ws, size_t ws_size,
                              hipStream_t stream) {
  const float* emb  = (const float*)d_in[0];
  const float* se   = (const float*)d_in[1];
  const float* slog = (const float*)d_in[2];
  const float* fc1w = (const float*)d_in[3];
  const float* fc1b = (const float*)d_in[4];
  const float* fc2w = (const float*)d_in[5];
  const float* fc2b = (const float*)d_in[6];
  const float* rw1  = (const float*)d_in[7];
  const float* rb1  = (const float*)d_in[8];
  const float* rw2  = (const float*)d_in[9];
  const float* rb2  = (const float*)d_in[10];
  float* out = (float*)d_out;
  unsigned char* ws = (unsigned char*)d_ws;

  // output 0: passthrough logits (B*N fp32)
  hipMemcpyAsync(out, slog, (size_t)B_SZ * N_SZ * sizeof(float),
                 hipMemcpyDeviceToDevice, stream);

  // weight prep (bf16 convert + transpose + swizzle into ws)
  prep_kernel<<<1568, 256, 0, stream>>>(rw1, rw2, fc1w, fc2w, ws);

  // forecast head
  f1_kernel<<<32, 256, 0, stream>>>(emb, fc1b, ws, ws + OFF_H);
  f2_kernel<<<dim3(32, 3), 256, 0, stream>>>(ws + OFF_H, ws + OFF_F2, fc2b,
                                             out + (size_t)B_SZ * N_SZ);

  // reconstruction heads (dominant)
  recon_kernel<<<dim3(32, 128), 256, 0, stream>>>(se, rb1, rb2, ws,
                                                  out + (size_t)B_SZ * N_SZ + (size_t)B_SZ * 384);
}

// Round 2
// 199.918 us; speedup vs baseline: 1.9423x; 1.9423x over previous
//
#include <hip/hip_runtime.h>
#include <hip/hip_bf16.h>
#include <stdint.h>

typedef __attribute__((ext_vector_type(8))) short bf16x8;
typedef __attribute__((ext_vector_type(4))) float f32x4;

#define DEVI static __device__ __forceinline__

// Problem sizes (fixed)
static constexpr int B_SZ = 4096, N_SZ = 128, H_SZ = 128, W_SZ = 64;

// ws layout (bytes), all 16B aligned
static constexpr size_t OFF_W1 = 0;                      // 128 * 128*128 bf16 = 4 MB (plain [n][h_out][h_in])
static constexpr size_t OFF_W2 = OFF_W1 + 4194304;       // 128 * 64*128 bf16 = 2 MB (plain [n][w][k])
static constexpr size_t OFF_F1 = OFF_W2 + 2097152;       // 128*128 bf16 = 32 KB (swizzled [o][h])
static constexpr size_t OFF_F2 = OFF_F1 + 32768;         // 384*128 bf16 = 96 KB (swizzled [o][j])
static constexpr size_t OFF_H  = OFF_F2 + 98304;         // 4096*128 bf16 = 1 MB (per-128-row tile, swizzled)

DEVI unsigned short f2bf(float f) {
  union { __hip_bfloat16 b; unsigned short u; } cv;
  cv.b = __float2bfloat16(f);
  return cv.u;
}
DEVI float bf2f(unsigned short u) {
  union { unsigned short u; __hip_bfloat16 b; } cv;
  cv.u = u;
  return __bfloat162float(cv.b);
}

// Read one MFMA fragment (8 contiguous bf16 along k) from a swizzled LDS tile.
// Tile layout: row stride 256B; 16B slot s stored at (s ^ (row&7)).
DEVI bf16x8 frag_ld(const unsigned char* base, int row, int kslot) {
  return *reinterpret_cast<const bf16x8*>(base + row * 256 + (((kslot ^ (row & 7)) << 4)));
}
// Unswizzled fragment read (global memory, 256B rows).
DEVI bf16x8 gfrag_ld(const unsigned char* base, int row, int kslot) {
  return *reinterpret_cast<const bf16x8*>(base + row * 256 + (kslot << 4));
}

// Stage an nrows x 128 fp32 tile (row stride in elems) into swizzled bf16 LDS.
DEVI void stage_f32_tile(const float* src, int row_stride, unsigned char* dst, int tid, int nrows) {
  for (int t = tid; t < nrows * 16; t += 256) {
    int row = t >> 4, s = t & 15;
    const float* p = src + (size_t)row * row_stride + s * 8;
    union { unsigned short u[8]; uint4 v; } pk;
#pragma unroll
    for (int j = 0; j < 8; ++j) pk.u[j] = f2bf(p[j]);
    *reinterpret_cast<uint4*>(dst + row * 256 + ((s ^ (row & 7)) << 4)) = pk.v;
  }
}

// ---------------- prep: convert+transpose weights into ws (bf16) ----------------
__global__ __launch_bounds__(256) void prep_kernel(const float* __restrict__ rw1,
                                                   const float* __restrict__ rw2,
                                                   const float* __restrict__ fc1w,
                                                   const float* __restrict__ fc2w,
                                                   unsigned char* __restrict__ ws) {
  const int T_W1 = 128 * 128 * 16;  // (n,s,c): W1t[n][c][h=s*8+j] = rw1[n][h][c]  (c = output h)
  const int T_W2 = 128 * 64 * 16;   // (n,s,w): W2t[n][w][k=s*8+j] = rw2[n][k][w]
  const int T_F1 = 128 * 16;        // (o,s):   F1s[o][h]          = fc1w[o][h]   (swizzled)
  const int T_F2 = 384 * 16;
  int id = blockIdx.x * 256 + threadIdx.x;
  if (id < T_W1) {
    int c = id & 127, rest = id >> 7;
    int s = rest & 15, n = rest >> 4;
    const float* src = rw1 + (size_t)n * 16384 + (size_t)(s * 8) * 128 + c;
    union { unsigned short u[8]; uint4 v; } pk;
#pragma unroll
    for (int j = 0; j < 8; ++j) pk.u[j] = f2bf(src[(size_t)j * 128]);
    size_t dst = OFF_W1 + ((size_t)n * 128 + c) * 256 + (size_t)(s << 4);
    *reinterpret_cast<uint4*>(ws + dst) = pk.v;
    return;
  }
  id -= T_W1;
  if (id < T_W2) {
    int w = id & 63, rest = id >> 6;
    int s = rest & 15, n = rest >> 4;
    const float* src = rw2 + (size_t)n * 8192 + (size_t)(s * 8) * 64 + w;
    union { unsigned short u[8]; uint4 v; } pk;
#pragma unroll
    for (int j = 0; j < 8; ++j) pk.u[j] = f2bf(src[(size_t)j * 64]);
    size_t dst = OFF_W2 + ((size_t)n * 64 + w) * 256 + (size_t)(s << 4);
    *reinterpret_cast<uint4*>(ws + dst) = pk.v;
    return;
  }
  id -= T_W2;
  if (id < T_F1) {
    int s = id & 15, o = id >> 4;
    const float* src = fc1w + (size_t)o * 128 + s * 8;
    union { unsigned short u[8]; uint4 v; } pk;
#pragma unroll
    for (int j = 0; j < 8; ++j) pk.u[j] = f2bf(src[j]);
    *reinterpret_cast<uint4*>(ws + OFF_F1 + (size_t)o * 256 + ((s ^ (o & 7)) << 4)) = pk.v;
    return;
  }
  id -= T_F1;
  if (id < T_F2) {
    int s = id & 15, o = id >> 4;
    const float* src = fc2w + (size_t)o * 128 + s * 8;
    union { unsigned short u[8]; uint4 v; } pk;
#pragma unroll
    for (int j = 0; j < 8; ++j) pk.u[j] = f2bf(src[j]);
    *reinterpret_cast<uint4*>(ws + OFF_F2 + (size_t)o * 256 + ((s ^ (o & 7)) << 4)) = pk.v;
  }
}

// ---------------- recon: per-node fused MLP, both GEMMs transposed ----------------
// GEMM1': C1t[h_out][b] = W1t . SE^T       (A = W1t from global, B = SE tile in LDS)
// GEMM2': C2t[w][b]     = W2t . hn^T       (A = W2t from global, B = hn tile in LDS)
// tmp output: bf16 [b][n][w] stored in the upper half of each b's 32KB out3 slot.
__global__ __launch_bounds__(256, 4) void recon_kernel(const float* __restrict__ se,
                                                       const float* __restrict__ rb1,
                                                       const float* __restrict__ rb2,
                                                       const unsigned char* __restrict__ ws,
                                                       float* __restrict__ out3) {
  __shared__ unsigned char sA[32768];  // SE tile (bf16 swizzled [b][h]), then reused for hn [b][k]

  const int tid = threadIdx.x;
  const int bt = blockIdx.x;   // 0..31 batch tiles of 128
  const int n = blockIdx.y;    // 0..127 node
  const int b0 = bt * 128;

  // stage SE tile: rows (b0+r), node n ; row stride = N*H
  stage_f32_tile(se + ((size_t)b0 * 128 + n) * 128, 128 * 128, sA, tid, 128);
  __syncthreads();

  const int wave = tid >> 6, lane = tid & 63;
  const int wm = wave >> 1, wq = wave & 1;  // wm: row-half of C', wq: b-half
  const int lr = lane & 15, lk = lane >> 4;

  // GEMM1': 128(h_out) x 128(b) x 128(k).  Waves 2x2, each 64x64.
  const unsigned char* w1b = ws + OFF_W1 + (size_t)n * 32768;
  f32x4 acc[4][4] = {};
#pragma unroll
  for (int kk = 0; kk < 4; ++kk) {
    const int slot = kk * 4 + lk;
    bf16x8 af[4], bfv[4];
#pragma unroll
    for (int m = 0; m < 4; ++m) af[m] = gfrag_ld(w1b, wm * 64 + m * 16 + lr, slot);
#pragma unroll
    for (int q = 0; q < 4; ++q) bfv[q] = frag_ld(sA, wq * 64 + q * 16 + lr, slot);
#pragma unroll
    for (int m = 0; m < 4; ++m)
#pragma unroll
      for (int q = 0; q < 4; ++q)
        acc[m][q] = __builtin_amdgcn_mfma_f32_16x16x32_bf16(af[m], bfv[q], acc[m][q], 0, 0, 0);
  }
  __syncthreads();  // all waves done reading SE from sA

  // epilogue1: hn[b][k] = relu(C1t[k][b] + rb1[k]) -> bf16 into sA (swizzled [b][k])
  // lane holds b = wq*64+q*16+lr (col), k = wm*64+m*16+lk*4+j (rows) -> 4 consecutive k = 8B write
  const float* b1p = rb1 + (size_t)n * 128;
#pragma unroll
  for (int m = 0; m < 4; ++m) {
    const int k0 = wm * 64 + m * 16 + lk * 4;
    const int s16 = k0 >> 3, half = (k0 >> 2) & 1;
#pragma unroll
    for (int q = 0; q < 4; ++q) {
      const int b = wq * 64 + q * 16 + lr;
      union { unsigned short u[4]; uint2 v; } pk;
#pragma unroll
      for (int j = 0; j < 4; ++j) {
        float v = acc[m][q][j] + b1p[k0 + j];
        v = v > 0.f ? v : 0.f;
        pk.u[j] = f2bf(v);
      }
      *reinterpret_cast<uint2*>(sA + b * 256 + ((s16 ^ (b & 7)) << 4) + half * 8) = pk.v;
    }
  }
  __syncthreads();

  // GEMM2': 64(w) x 128(b) x 128(k).  Waves 2x2, each 32x64.
  const unsigned char* w2b = ws + OFF_W2 + (size_t)n * 16384;
  f32x4 acc2[2][4] = {};
#pragma unroll
  for (int kk = 0; kk < 4; ++kk) {
    const int slot = kk * 4 + lk;
    bf16x8 af[2], bfv[4];
#pragma unroll
    for (int m = 0; m < 2; ++m) af[m] = gfrag_ld(w2b, wm * 32 + m * 16 + lr, slot);
#pragma unroll
    for (int q = 0; q < 4; ++q) bfv[q] = frag_ld(sA, wq * 64 + q * 16 + lr, slot);
#pragma unroll
    for (int m = 0; m < 2; ++m)
#pragma unroll
      for (int q = 0; q < 4; ++q)
        acc2[m][q] = __builtin_amdgcn_mfma_f32_16x16x32_bf16(af[m], bfv[q], acc2[m][q], 0, 0, 0);
  }

  // epilogue2: tmp[b][n][w] bf16, stashed at float-offset 4096 of b's out3 slot.
  // lane holds b (col), w = wm*32+m*16+lk*4+j -> 4 consecutive w = 8B store.
  unsigned short* outus = reinterpret_cast<unsigned short*>(out3);
  const float* b2p = rb2 + (size_t)n * 64;
#pragma unroll
  for (int m = 0; m < 2; ++m) {
    const int w0 = wm * 32 + m * 16 + lk * 4;
#pragma unroll
    for (int q = 0; q < 4; ++q) {
      const int b = b0 + wq * 64 + q * 16 + lr;
      union { unsigned short u[4]; uint2 v; } pk;
#pragma unroll
      for (int j = 0; j < 4; ++j) pk.u[j] = f2bf(acc2[m][q][j] + b2p[w0 + j]);
      *reinterpret_cast<uint2*>(outus + (size_t)b * 16384 + 8192 + n * 64 + w0) = pk.v;
    }
  }
}

// ---------------- transpose: tmp bf16 [b][n][w] -> out3 fp32 [b][w][n] ----------------
__global__ __launch_bounds__(256) void transpose_kernel(float* __restrict__ out3) {
  __shared__ unsigned short lds[128][68];
  const int b = blockIdx.x, tid = threadIdx.x;
  const unsigned short* t = reinterpret_cast<const unsigned short*>(out3) + (size_t)b * 16384 + 8192;
  for (int c = tid; c < 1024; c += 256) {
    union { uint4 v; unsigned short u[8]; } pk;
    pk.v = *reinterpret_cast<const uint4*>(t + c * 8);
    const int n = c >> 3, w0 = (c & 7) * 8;
#pragma unroll
    for (int j = 0; j < 8; ++j) lds[n][w0 + j] = pk.u[j];
  }
  __syncthreads();
  float* dst = out3 + (size_t)b * 8192;
  for (int oc = tid; oc < 2048; oc += 256) {
    const int w = oc >> 5, n0 = (oc & 31) * 4;
    float4 v;
    v.x = bf2f(lds[n0 + 0][w]);
    v.y = bf2f(lds[n0 + 1][w]);
    v.z = bf2f(lds[n0 + 2][w]);
    v.w = bf2f(lds[n0 + 3][w]);
    *reinterpret_cast<float4*>(dst + oc * 4) = v;
  }
}

// ---------------- forecast stage 1: h = relu(emb @ fc1^T + b1) -> ws (bf16, tile-swizzled) ----------------
__global__ __launch_bounds__(256) void f1_kernel(const float* __restrict__ emb,
                                                 const float* __restrict__ fc1b,
                                                 const unsigned char* __restrict__ ws,
                                                 unsigned char* __restrict__ hsw) {
  __shared__ unsigned char sA[32768];
  __shared__ unsigned char sB[32768];
  const int tid = threadIdx.x;
  const int bt = blockIdx.x;
  const int b0 = bt * 128;
  {
    const uint4* wp = reinterpret_cast<const uint4*>(ws + OFF_F1);
    uint4* d = reinterpret_cast<uint4*>(sB);
    for (int c = tid; c < 2048; c += 256) d[c] = wp[c];
  }
  stage_f32_tile(emb + (size_t)b0 * 128, 128, sA, tid, 128);
  __syncthreads();

  const int wave = tid >> 6, lane = tid & 63;
  const int wm = wave >> 1, wn = wave & 1;
  const int lr = lane & 15, lk = lane >> 4;

  f32x4 acc[4][4] = {};
#pragma unroll
  for (int kk = 0; kk < 4; ++kk) {
    bf16x8 af[4], bfv[4];
#pragma unroll
    for (int m = 0; m < 4; ++m) af[m] = frag_ld(sA, wm * 64 + m * 16 + lr, kk * 4 + lk);
#pragma unroll
    for (int q = 0; q < 4; ++q) bfv[q] = frag_ld(sB, wn * 64 + q * 16 + lr, kk * 4 + lk);
#pragma unroll
    for (int m = 0; m < 4; ++m)
#pragma unroll
      for (int q = 0; q < 4; ++q)
        acc[m][q] = __builtin_amdgcn_mfma_f32_16x16x32_bf16(af[m], bfv[q], acc[m][q], 0, 0, 0);
  }

  unsigned char* tile = hsw + (size_t)bt * 32768;
#pragma unroll
  for (int q = 0; q < 4; ++q) {
    int c = wn * 64 + q * 16 + lr;
    float bias = fc1b[c];
#pragma unroll
    for (int m = 0; m < 4; ++m) {
#pragma unroll
      for (int j = 0; j < 4; ++j) {
        int r = wm * 64 + m * 16 + lk * 4 + j;
        float v = acc[m][q][j] + bias;
        v = v > 0.f ? v : 0.f;
        *reinterpret_cast<unsigned short*>(tile + r * 256 + ((c * 2) ^ ((r & 7) << 4))) = f2bf(v);
      }
    }
  }
}

// ---------------- forecast stage 2: forecast = h @ fc2^T + b2 ----------------
__global__ __launch_bounds__(256) void f2_kernel(const unsigned char* __restrict__ hsw,
                                                 const unsigned char* __restrict__ f2s,
                                                 const float* __restrict__ fc2b,
                                                 float* __restrict__ out2) {
  __shared__ unsigned char sA[32768];
  __shared__ unsigned char sB[32768];
  const int tid = threadIdx.x;
  const int bt = blockIdx.x;      // 0..31
  const int ch = blockIdx.y;      // 0..2 (chunks of 128 output cols)
  const int b0 = bt * 128;
  {
    const uint4* ap = reinterpret_cast<const uint4*>(hsw + (size_t)bt * 32768);
    uint4* da = reinterpret_cast<uint4*>(sA);
    for (int c = tid; c < 2048; c += 256) da[c] = ap[c];
    const uint4* bp = reinterpret_cast<const uint4*>(f2s + (size_t)ch * 32768);
    uint4* db = reinterpret_cast<uint4*>(sB);
    for (int c = tid; c < 2048; c += 256) db[c] = bp[c];
  }
  __syncthreads();

  const int wave = tid >> 6, lane = tid & 63;
  const int wm = wave >> 1, wn = wave & 1;
  const int lr = lane & 15, lk = lane >> 4;

  f32x4 acc[4][4] = {};
#pragma unroll
  for (int kk = 0; kk < 4; ++kk) {
    bf16x8 af[4], bfv[4];
#pragma unroll
    for (int m = 0; m < 4; ++m) af[m] = frag_ld(sA, wm * 64 + m * 16 + lr, kk * 4 + lk);
#pragma unroll
    for (int q = 0; q < 4; ++q) bfv[q] = frag_ld(sB, wn * 64 + q * 16 + lr, kk * 4 + lk);
#pragma unroll
    for (int m = 0; m < 4; ++m)
#pragma unroll
      for (int q = 0; q < 4; ++q)
        acc[m][q] = __builtin_amdgcn_mfma_f32_16x16x32_bf16(af[m], bfv[q], acc[m][q], 0, 0, 0);
  }

#pragma unroll
  for (int q = 0; q < 4; ++q) {
    int o = ch * 128 + wn * 64 + q * 16 + lr;
    float bias = fc2b[o];
#pragma unroll
    for (int m = 0; m < 4; ++m) {
#pragma unroll
      for (int j = 0; j < 4; ++j) {
        int r = wm * 64 + m * 16 + lk * 4 + j;
        out2[(size_t)(b0 + r) * 384 + o] = acc[m][q][j] + bias;
      }
    }
  }
}

extern "C" void kernel_launch(void* const* d_in, const int* in_sizes, int n_in,
                              void* d_out, int out_size, void* d_ws, size_t ws_size,
                              hipStream_t stream) {
  const float* emb  = (const float*)d_in[0];
  const float* se   = (const float*)d_in[1];
  const float* slog = (const float*)d_in[2];
  const float* fc1w = (const float*)d_in[3];
  const float* fc1b = (const float*)d_in[4];
  const float* fc2w = (const float*)d_in[5];
  const float* fc2b = (const float*)d_in[6];
  const float* rw1  = (const float*)d_in[7];
  const float* rb1  = (const float*)d_in[8];
  const float* rw2  = (const float*)d_in[9];
  const float* rb2  = (const float*)d_in[10];
  float* out = (float*)d_out;
  unsigned char* ws = (unsigned char*)d_ws;

  // output 0: passthrough logits (B*N fp32)
  hipMemcpyAsync(out, slog, (size_t)B_SZ * N_SZ * sizeof(float),
                 hipMemcpyDeviceToDevice, stream);

  // weight prep (bf16 convert + transpose into ws)
  prep_kernel<<<1568, 256, 0, stream>>>(rw1, rw2, fc1w, fc2w, ws);

  // forecast head
  f1_kernel<<<32, 256, 0, stream>>>(emb, fc1b, ws, ws + OFF_H);
  f2_kernel<<<dim3(32, 3), 256, 0, stream>>>(ws + OFF_H, ws + OFF_F2, fc2b,
                                             out + (size_t)B_SZ * N_SZ);

  // reconstruction heads (dominant): transposed-GEMM recon -> bf16 tmp -> transpose
  float* out3 = out + (size_t)B_SZ * N_SZ + (size_t)B_SZ * 384;
  recon_kernel<<<dim3(32, 128), 256, 0, stream>>>(se, rb1, rb2, ws, out3);
  transpose_kernel<<<4096, 256, 0, stream>>>(out3);
}

// Round 3
// 151.609 us; speedup vs baseline: 2.5612x; 1.3186x over previous
//
#include <hip/hip_runtime.h>
#include <hip/hip_bf16.h>
#include <stdint.h>

typedef __attribute__((ext_vector_type(8))) short bf16x8;
typedef __attribute__((ext_vector_type(4))) float f32x4;

#define DEVI static __device__ __forceinline__

// Problem sizes (fixed)
static constexpr int B_SZ = 4096, N_SZ = 128, H_SZ = 128, W_SZ = 64;

// ws layout (bytes), all 16B aligned
static constexpr size_t OFF_W1 = 0;                      // 128 * 128*128 bf16 = 4 MB (swizzled [n][c][h])
static constexpr size_t OFF_W2 = OFF_W1 + 4194304;       // 128 * 64*128 bf16 = 2 MB (swizzled [n][w][k])
static constexpr size_t OFF_F1 = OFF_W2 + 2097152;       // 128*128 bf16 = 32 KB (swizzled [o][h])
static constexpr size_t OFF_F2 = OFF_F1 + 32768;         // 384*128 bf16 = 96 KB (swizzled [o][j])
static constexpr size_t OFF_H  = OFF_F2 + 98304;         // 4096*128 bf16 = 1 MB (per-128-row tile, swizzled)

DEVI unsigned short f2bf(float f) {
  union { __hip_bfloat16 b; unsigned short u; } cv;
  cv.b = __float2bfloat16(f);
  return cv.u;
}
DEVI float bf2f(unsigned short u) {
  union { unsigned int i; float f; } cv;
  cv.i = ((unsigned int)u) << 16;
  return cv.f;
}

// Read one MFMA fragment (8 contiguous bf16 along k) from a swizzled LDS tile.
// Tile layout: row stride 256B; 16B slot s stored at (s ^ (row&7)).
DEVI bf16x8 frag_ld(const unsigned char* base, int row, int kslot) {
  return *reinterpret_cast<const bf16x8*>(base + row * 256 + (((kslot ^ (row & 7)) << 4)));
}

// Stage an nrows x 128 fp32 tile (row stride in elems) into swizzled bf16 LDS.
DEVI void stage_f32_tile(const float* src, int row_stride, unsigned char* dst, int tid, int nrows) {
  for (int t = tid; t < nrows * 16; t += 256) {
    int row = t >> 4, s = t & 15;
    const float* p = src + (size_t)row * row_stride + s * 8;
    union { unsigned short u[8]; uint4 v; } pk;
#pragma unroll
    for (int j = 0; j < 8; ++j) pk.u[j] = f2bf(p[j]);
    *reinterpret_cast<uint4*>(dst + row * 256 + ((s ^ (row & 7)) << 4)) = pk.v;
  }
}

// ---------------- prep: convert+transpose weights into ws (bf16, pre-swizzled) ----------------
__global__ __launch_bounds__(256) void prep_kernel(const float* __restrict__ rw1,
                                                   const float* __restrict__ rw2,
                                                   const float* __restrict__ fc1w,
                                                   const float* __restrict__ fc2w,
                                                   unsigned char* __restrict__ ws) {
  const int T_W1 = 128 * 128 * 16;  // (n,s,c): W1s[n][c][h=s*8+j] = rw1[n][h][c]  (c = output h)
  const int T_W2 = 128 * 64 * 16;   // (n,s,w): W2s[n][w][k=s*8+j] = rw2[n][k][w]
  const int T_F1 = 128 * 16;        // (o,s):   F1s[o][h]          = fc1w[o][h]
  const int T_F2 = 384 * 16;
  int id = blockIdx.x * 256 + threadIdx.x;
  if (id < T_W1) {
    int c = id & 127, rest = id >> 7;
    int s = rest & 15, n = rest >> 4;
    const float* src = rw1 + (size_t)n * 16384 + (size_t)(s * 8) * 128 + c;
    union { unsigned short u[8]; uint4 v; } pk;
#pragma unroll
    for (int j = 0; j < 8; ++j) pk.u[j] = f2bf(src[(size_t)j * 128]);
    size_t dst = OFF_W1 + ((size_t)n * 128 + c) * 256 + (size_t)((s ^ (c & 7)) << 4);
    *reinterpret_cast<uint4*>(ws + dst) = pk.v;
    return;
  }
  id -= T_W1;
  if (id < T_W2) {
    int w = id & 63, rest = id >> 6;
    int s = rest & 15, n = rest >> 4;
    const float* src = rw2 + (size_t)n * 8192 + (size_t)(s * 8) * 64 + w;
    union { unsigned short u[8]; uint4 v; } pk;
#pragma unroll
    for (int j = 0; j < 8; ++j) pk.u[j] = f2bf(src[(size_t)j * 64]);
    size_t dst = OFF_W2 + ((size_t)n * 64 + w) * 256 + (size_t)((s ^ (w & 7)) << 4);
    *reinterpret_cast<uint4*>(ws + dst) = pk.v;
    return;
  }
  id -= T_W2;
  if (id < T_F1) {
    int s = id & 15, o = id >> 4;
    const float* src = fc1w + (size_t)o * 128 + s * 8;
    union { unsigned short u[8]; uint4 v; } pk;
#pragma unroll
    for (int j = 0; j < 8; ++j) pk.u[j] = f2bf(src[j]);
    *reinterpret_cast<uint4*>(ws + OFF_F1 + (size_t)o * 256 + ((s ^ (o & 7)) << 4)) = pk.v;
    return;
  }
  id -= T_F1;
  if (id < T_F2) {
    int s = id & 15, o = id >> 4;
    const float* src = fc2w + (size_t)o * 128 + s * 8;
    union { unsigned short u[8]; uint4 v; } pk;
#pragma unroll
    for (int j = 0; j < 8; ++j) pk.u[j] = f2bf(src[j]);
    *reinterpret_cast<uint4*>(ws + OFF_F2 + (size_t)o * 256 + ((s ^ (o & 7)) << 4)) = pk.v;
  }
}

// ---------------- recon v3: per-node fused MLP, 8x 64-row b-subtiles, dbuf SE pipeline ----------------
// GEMM1': C1t[h_out][b] = W1t . SE^T   (A = W1 in LDS, B = SE tile in LDS)
// GEMM2': C2t[w][b]     = W2t . hn^T   (A = W2 in LDS, B = hn tile in LDS, hn overwrites SE)
// tmp output: bf16 [b][n][w] stashed in the upper half of each b's 32KB out3 slot.
__global__ __launch_bounds__(256, 2) void recon_kernel(const float* __restrict__ se,
                                                       const float* __restrict__ rb1,
                                                       const float* __restrict__ rb2,
                                                       const unsigned char* __restrict__ ws,
                                                       float* __restrict__ out3) {
  __shared__ unsigned char sW1[32768];     // W1s[n] (swizzled rows c, 256B)
  __shared__ unsigned char sW2[16384];     // W2s[n] (swizzled rows w, 256B)
  __shared__ unsigned char sSE[2][16384];  // SE/hn 64-row tiles (swizzled rows b, 256B)

  const int tid = threadIdx.x;
  const int btg = blockIdx.x;  // 0..7  -> 512 b-rows each
  const int n = blockIdx.y;    // 0..127 node
  const int b0 = btg * 512;

  // stage weights (bf16+swizzled in ws): linear uint4 copies
  {
    const uint4* w1p = reinterpret_cast<const uint4*>(ws + OFF_W1 + (size_t)n * 32768);
    uint4* d1 = reinterpret_cast<uint4*>(sW1);
    for (int c = tid; c < 2048; c += 256) d1[c] = w1p[c];
    const uint4* w2p = reinterpret_cast<const uint4*>(ws + OFF_W2 + (size_t)n * 16384);
    uint4* d2 = reinterpret_cast<uint4*>(sW2);
    for (int c = tid; c < 1024; c += 256) d2[c] = w2p[c];
  }
  // stage SE subtile 0
  stage_f32_tile(se + ((size_t)b0 * 128 + n) * 128, 128 * 128, sSE[0], tid, 64);

  const int wave = tid >> 6, lane = tid & 63;
  const int wm = wave >> 1, wq = wave & 1;  // wm: out-row half, wq: b half (32 each)
  const int lr = lane & 15, lk = lane >> 4;

  // preload biases (constant per lane across all tiles)
  float bias1[4][4], bias2[2][4];
#pragma unroll
  for (int m = 0; m < 4; ++m)
#pragma unroll
    for (int j = 0; j < 4; ++j) bias1[m][j] = rb1[(size_t)n * 128 + wm * 64 + m * 16 + lk * 4 + j];
#pragma unroll
  for (int m = 0; m < 2; ++m)
#pragma unroll
    for (int j = 0; j < 4; ++j) bias2[m][j] = rb2[(size_t)n * 64 + wm * 32 + m * 16 + lk * 4 + j];

  unsigned short* outus = reinterpret_cast<unsigned short*>(out3);
  __syncthreads();

  // prefetch register file for next tile: 4 chunks x 8 fp32
  float4 fra[4], frb[4];

  for (int t = 0; t < 8; ++t) {
    unsigned char* bufc = sSE[t & 1];
    unsigned char* bufn = sSE[(t + 1) & 1];

    // issue next tile's global loads early (hide HBM latency under G1/epi/G2)
    if (t < 7) {
      const float* sb = se + ((size_t)(b0 + (t + 1) * 64) * 128 + n) * 128;
#pragma unroll
      for (int k = 0; k < 4; ++k) {
        int c = tid + k * 256;
        int row = c >> 4, s = c & 15;
        const float* p = sb + (size_t)row * 16384 + s * 8;
        fra[k] = *reinterpret_cast<const float4*>(p);
        frb[k] = *reinterpret_cast<const float4*>(p + 4);
      }
    }

    // GEMM1': 128(h_out) x 64(b) x 128(k); wave owns 64 x 32
    f32x4 acc[4][2] = {};
#pragma unroll
    for (int kk = 0; kk < 4; ++kk) {
      const int slot = kk * 4 + lk;
      bf16x8 af[4], bv[2];
#pragma unroll
      for (int m = 0; m < 4; ++m) af[m] = frag_ld(sW1, wm * 64 + m * 16 + lr, slot);
#pragma unroll
      for (int q = 0; q < 2; ++q) bv[q] = frag_ld(bufc, wq * 32 + q * 16 + lr, slot);
#pragma unroll
      for (int m = 0; m < 4; ++m)
#pragma unroll
        for (int q = 0; q < 2; ++q)
          acc[m][q] = __builtin_amdgcn_mfma_f32_16x16x32_bf16(af[m], bv[q], acc[m][q], 0, 0, 0);
    }
    __syncthreads();  // G1 done reading SE from bufc

    // epilogue1: hn[b][k] = relu(C1t[k][b] + rb1[k]) -> bf16 back into bufc
    // lane: b = wq*32+q*16+lr, k = wm*64+m*16+lk*4+j  -> 8B write
#pragma unroll
    for (int m = 0; m < 4; ++m) {
      const int k0 = wm * 64 + m * 16 + lk * 4;
      const int s16 = k0 >> 3, half = (k0 >> 2) & 1;
#pragma unroll
      for (int q = 0; q < 2; ++q) {
        const int b = wq * 32 + q * 16 + lr;
        union { unsigned short u[4]; uint2 v; } pk;
#pragma unroll
        for (int j = 0; j < 4; ++j) {
          float v = acc[m][q][j] + bias1[m][j];
          v = v > 0.f ? v : 0.f;
          pk.u[j] = f2bf(v);
        }
        *reinterpret_cast<uint2*>(bufc + b * 256 + ((s16 ^ (b & 7)) << 4) + half * 8) = pk.v;
      }
    }
    __syncthreads();

    // GEMM2': 64(w) x 64(b) x 128(k); wave owns 32 x 32
    f32x4 acc2[2][2] = {};
#pragma unroll
    for (int kk = 0; kk < 4; ++kk) {
      const int slot = kk * 4 + lk;
      bf16x8 af[2], bv[2];
#pragma unroll
      for (int m = 0; m < 2; ++m) af[m] = frag_ld(sW2, wm * 32 + m * 16 + lr, slot);
#pragma unroll
      for (int q = 0; q < 2; ++q) bv[q] = frag_ld(bufc, wq * 32 + q * 16 + lr, slot);
#pragma unroll
      for (int m = 0; m < 2; ++m)
#pragma unroll
        for (int q = 0; q < 2; ++q)
          acc2[m][q] = __builtin_amdgcn_mfma_f32_16x16x32_bf16(af[m], bv[q], acc2[m][q], 0, 0, 0);
    }

    // write prefetched SE(t+1) into the other buffer (overlapped with G2/stores)
    if (t < 7) {
#pragma unroll
      for (int k = 0; k < 4; ++k) {
        int c = tid + k * 256;
        int row = c >> 4, s = c & 15;
        union { unsigned short u[8]; uint4 v; } pk;
#pragma unroll
        for (int j = 0; j < 4; ++j) pk.u[j] = f2bf(fra[k][j]);
#pragma unroll
        for (int j = 0; j < 4; ++j) pk.u[4 + j] = f2bf(frb[k][j]);
        *reinterpret_cast<uint4*>(bufn + row * 256 + ((s ^ (row & 7)) << 4)) = pk.v;
      }
    }

    // epilogue2: tmp[b][n][w] bf16 at float-offset 4096 of b's out3 slot
    const int bt0 = b0 + t * 64;
#pragma unroll
    for (int m = 0; m < 2; ++m) {
      const int w0 = wm * 32 + m * 16 + lk * 4;
#pragma unroll
      for (int q = 0; q < 2; ++q) {
        const int b = bt0 + wq * 32 + q * 16 + lr;
        union { unsigned short u[4]; uint2 v; } pk;
#pragma unroll
        for (int j = 0; j < 4; ++j) pk.u[j] = f2bf(acc2[m][q][j] + bias2[m][j]);
        *reinterpret_cast<uint2*>(outus + (size_t)b * 16384 + 8192 + n * 64 + w0) = pk.v;
      }
    }
    __syncthreads();  // SE(t+1) staged; hn(t) fully consumed
  }
}

// ---------------- transpose: tmp bf16 [b][n][w] -> out3 fp32 [b][w][n], LDS-free ----------------
// wave g handles w-group g (8 w). Lane = n (and n+64). Reads 16B/lane; writes
// 64-lane-contiguous 256B fp32 rows. Reads all before writes (tmp overlaps dst upper half).
__global__ __launch_bounds__(256) void transpose_kernel(float* __restrict__ out3) {
  const int b = blockIdx.x, wave = threadIdx.x >> 6, lane = threadIdx.x & 63;
  const unsigned short* t = reinterpret_cast<const unsigned short*>(out3) + (size_t)b * 16384 + 8192;
  float* dst = out3 + (size_t)b * 8192;
  uint4 r[2][2];
#pragma unroll
  for (int half = 0; half < 2; ++half) {
    const int g = half * 4 + wave;
    r[half][0] = *reinterpret_cast<const uint4*>(t + lane * 64 + g * 8);
    r[half][1] = *reinterpret_cast<const uint4*>(t + (size_t)(lane + 64) * 64 + g * 8);
  }
  __syncthreads();  // all reads done before dst writes clobber the tmp region
#pragma unroll
  for (int half = 0; half < 2; ++half) {
    const int g = half * 4 + wave;
    union { uint4 v; unsigned short u[8]; } p0, p1;
    p0.v = r[half][0];
    p1.v = r[half][1];
#pragma unroll
    for (int j = 0; j < 8; ++j) {
      dst[(g * 8 + j) * 128 + lane] = bf2f(p0.u[j]);
      dst[(g * 8 + j) * 128 + lane + 64] = bf2f(p1.u[j]);
    }
  }
}

// ---------------- forecast stage 1: h = relu(emb @ fc1^T + b1) -> ws (bf16, tile-swizzled) ----------------
__global__ __launch_bounds__(256) void f1_kernel(const float* __restrict__ emb,
                                                 const float* __restrict__ fc1b,
                                                 const unsigned char* __restrict__ ws,
                                                 unsigned char* __restrict__ hsw) {
  __shared__ unsigned char sA[32768];
  __shared__ unsigned char sB[32768];
  const int tid = threadIdx.x;
  const int bt = blockIdx.x;
  const int b0 = bt * 128;
  {
    const uint4* wp = reinterpret_cast<const uint4*>(ws + OFF_F1);
    uint4* d = reinterpret_cast<uint4*>(sB);
    for (int c = tid; c < 2048; c += 256) d[c] = wp[c];
  }
  stage_f32_tile(emb + (size_t)b0 * 128, 128, sA, tid, 128);
  __syncthreads();

  const int wave = tid >> 6, lane = tid & 63;
  const int wm = wave >> 1, wn = wave & 1;
  const int lr = lane & 15, lk = lane >> 4;

  f32x4 acc[4][4] = {};
#pragma unroll
  for (int kk = 0; kk < 4; ++kk) {
    bf16x8 af[4], bfv[4];
#pragma unroll
    for (int m = 0; m < 4; ++m) af[m] = frag_ld(sA, wm * 64 + m * 16 + lr, kk * 4 + lk);
#pragma unroll
    for (int q = 0; q < 4; ++q) bfv[q] = frag_ld(sB, wn * 64 + q * 16 + lr, kk * 4 + lk);
#pragma unroll
    for (int m = 0; m < 4; ++m)
#pragma unroll
      for (int q = 0; q < 4; ++q)
        acc[m][q] = __builtin_amdgcn_mfma_f32_16x16x32_bf16(af[m], bfv[q], acc[m][q], 0, 0, 0);
  }

  unsigned char* tile = hsw + (size_t)bt * 32768;
#pragma unroll
  for (int q = 0; q < 4; ++q) {
    int c = wn * 64 + q * 16 + lr;
    float bias = fc1b[c];
#pragma unroll
    for (int m = 0; m < 4; ++m) {
#pragma unroll
      for (int j = 0; j < 4; ++j) {
        int r = wm * 64 + m * 16 + lk * 4 + j;
        float v = acc[m][q][j] + bias;
        v = v > 0.f ? v : 0.f;
        *reinterpret_cast<unsigned short*>(tile + r * 256 + ((c * 2) ^ ((r & 7) << 4))) = f2bf(v);
      }
    }
  }
}

// ---------------- forecast stage 2: forecast = h @ fc2^T + b2 ----------------
__global__ __launch_bounds__(256) void f2_kernel(const unsigned char* __restrict__ hsw,
                                                 const unsigned char* __restrict__ f2s,
                                                 const float* __restrict__ fc2b,
                                                 float* __restrict__ out2) {
  __shared__ unsigned char sA[32768];
  __shared__ unsigned char sB[32768];
  const int tid = threadIdx.x;
  const int bt = blockIdx.x;      // 0..31
  const int ch = blockIdx.y;      // 0..2 (chunks of 128 output cols)
  const int b0 = bt * 128;
  {
    const uint4* ap = reinterpret_cast<const uint4*>(hsw + (size_t)bt * 32768);
    uint4* da = reinterpret_cast<uint4*>(sA);
    for (int c = tid; c < 2048; c += 256) da[c] = ap[c];
    const uint4* bp = reinterpret_cast<const uint4*>(f2s + (size_t)ch * 32768);
    uint4* db = reinterpret_cast<uint4*>(sB);
    for (int c = tid; c < 2048; c += 256) db[c] = bp[c];
  }
  __syncthreads();

  const int wave = tid >> 6, lane = tid & 63;
  const int wm = wave >> 1, wn = wave & 1;
  const int lr = lane & 15, lk = lane >> 4;

  f32x4 acc[4][4] = {};
#pragma unroll
  for (int kk = 0; kk < 4; ++kk) {
    bf16x8 af[4], bfv[4];
#pragma unroll
    for (int m = 0; m < 4; ++m) af[m] = frag_ld(sA, wm * 64 + m * 16 + lr, kk * 4 + lk);
#pragma unroll
    for (int q = 0; q < 4; ++q) bfv[q] = frag_ld(sB, wn * 64 + q * 16 + lr, kk * 4 + lk);
#pragma unroll
    for (int m = 0; m < 4; ++m)
#pragma unroll
      for (int q = 0; q < 4; ++q)
        acc[m][q] = __builtin_amdgcn_mfma_f32_16x16x32_bf16(af[m], bfv[q], acc[m][q], 0, 0, 0);
  }

#pragma unroll
  for (int q = 0; q < 4; ++q) {
    int o = ch * 128 + wn * 64 + q * 16 + lr;
    float bias = fc2b[o];
#pragma unroll
    for (int m = 0; m < 4; ++m) {
#pragma unroll
      for (int j = 0; j < 4; ++j) {
        int r = wm * 64 + m * 16 + lk * 4 + j;
        out2[(size_t)(b0 + r) * 384 + o] = acc[m][q][j] + bias;
      }
    }
  }
}

extern "C" void kernel_launch(void* const* d_in, const int* in_sizes, int n_in,
                              void* d_out, int out_size, void* d_ws, size_t ws_size,
                              hipStream_t stream) {
  const float* emb  = (const float*)d_in[0];
  const float* se   = (const float*)d_in[1];
  const float* slog = (const float*)d_in[2];
  const float* fc1w = (const float*)d_in[3];
  const float* fc1b = (const float*)d_in[4];
  const float* fc2w = (const float*)d_in[5];
  const float* fc2b = (const float*)d_in[6];
  const float* rw1  = (const float*)d_in[7];
  const float* rb1  = (const float*)d_in[8];
  const float* rw2  = (const float*)d_in[9];
  const float* rb2  = (const float*)d_in[10];
  float* out = (float*)d_out;
  unsigned char* ws = (unsigned char*)d_ws;

  // output 0: passthrough logits (B*N fp32)
  hipMemcpyAsync(out, slog, (size_t)B_SZ * N_SZ * sizeof(float),
                 hipMemcpyDeviceToDevice, stream);

  // weight prep (bf16 convert + transpose + swizzle into ws)
  prep_kernel<<<1568, 256, 0, stream>>>(rw1, rw2, fc1w, fc2w, ws);

  // forecast head
  f1_kernel<<<32, 256, 0, stream>>>(emb, fc1b, ws, ws + OFF_H);
  f2_kernel<<<dim3(32, 3), 256, 0, stream>>>(ws + OFF_H, ws + OFF_F2, fc2b,
                                             out + (size_t)B_SZ * N_SZ);

  // reconstruction heads (dominant): pipelined recon -> bf16 tmp -> transpose
  float* out3 = out + (size_t)B_SZ * N_SZ + (size_t)B_SZ * 384;
  recon_kernel<<<dim3(8, 128), 256, 0, stream>>>(se, rb1, rb2, ws, out3);
  transpose_kernel<<<4096, 256, 0, stream>>>(out3);
}

// Round 4
// 140.890 us; speedup vs baseline: 2.7560x; 1.0761x over previous
//
#include <hip/hip_runtime.h>
#include <hip/hip_bf16.h>
#include <stdint.h>

typedef __attribute__((ext_vector_type(8))) short bf16x8;
typedef __attribute__((ext_vector_type(4))) float f32x4;

#define DEVI static __device__ __forceinline__

// Problem sizes (fixed)
static constexpr int B_SZ = 4096, N_SZ = 128, H_SZ = 128, W_SZ = 64;

// ws layout (bytes), all 16B aligned
static constexpr size_t OFF_W1 = 0;                      // 128 * 128*128 bf16 = 4 MB (UNswizzled [n][c][h])
static constexpr size_t OFF_W2 = OFF_W1 + 4194304;       // 128 * 64*128 bf16 = 2 MB (UNswizzled [n][w][k])
static constexpr size_t OFF_F1 = OFF_W2 + 2097152;       // 128*128 bf16 = 32 KB (swizzled [o][h])
static constexpr size_t OFF_F2 = OFF_F1 + 32768;         // 384*128 bf16 = 96 KB (swizzled [o][j])
static constexpr size_t OFF_H  = OFF_F2 + 98304;         // 4096*128 bf16 = 1 MB (per-128-row tile, swizzled)

DEVI unsigned short f2bf(float f) {
  union { __hip_bfloat16 b; unsigned short u; } cv;
  cv.b = __float2bfloat16(f);
  return cv.u;
}
DEVI float bf2f(unsigned short u) {
  union { unsigned int i; float f; } cv;
  cv.i = ((unsigned int)u) << 16;
  return cv.f;
}

// Read one MFMA fragment (8 contiguous bf16 along k) from a swizzled LDS tile.
// Tile layout: row stride 256B; 16B slot s stored at (s ^ (row&7)).
DEVI bf16x8 frag_ld(const unsigned char* base, int row, int kslot) {
  return *reinterpret_cast<const bf16x8*>(base + row * 256 + (((kslot ^ (row & 7)) << 4)));
}
// Unswizzled fragment read (global memory, 256B rows).
DEVI bf16x8 gfrag_ld(const unsigned char* base, int row, int kslot) {
  return *reinterpret_cast<const bf16x8*>(base + row * 256 + (kslot << 4));
}

// Stage an nrows x 128 fp32 tile (row stride in elems) into swizzled bf16 LDS.
DEVI void stage_f32_tile(const float* src, int row_stride, unsigned char* dst, int tid, int nrows) {
  for (int t = tid; t < nrows * 16; t += 256) {
    int row = t >> 4, s = t & 15;
    const float* p = src + (size_t)row * row_stride + s * 8;
    union { unsigned short u[8]; uint4 v; } pk;
#pragma unroll
    for (int j = 0; j < 8; ++j) pk.u[j] = f2bf(p[j]);
    *reinterpret_cast<uint4*>(dst + row * 256 + ((s ^ (row & 7)) << 4)) = pk.v;
  }
}

// ---------------- prep: convert+transpose weights into ws (bf16) ----------------
__global__ __launch_bounds__(256) void prep_kernel(const float* __restrict__ rw1,
                                                   const float* __restrict__ rw2,
                                                   const float* __restrict__ fc1w,
                                                   const float* __restrict__ fc2w,
                                                   unsigned char* __restrict__ ws) {
  const int T_W1 = 128 * 128 * 16;  // (n,s,c): W1t[n][c][h=s*8+j] = rw1[n][h][c]  (c = output h)
  const int T_W2 = 128 * 64 * 16;   // (n,s,w): W2t[n][w][k=s*8+j] = rw2[n][k][w]
  const int T_F1 = 128 * 16;        // (o,s):   F1s[o][h]          = fc1w[o][h]  (swizzled)
  const int T_F2 = 384 * 16;
  int id = blockIdx.x * 256 + threadIdx.x;
  if (id < T_W1) {
    int c = id & 127, rest = id >> 7;
    int s = rest & 15, n = rest >> 4;
    const float* src = rw1 + (size_t)n * 16384 + (size_t)(s * 8) * 128 + c;
    union { unsigned short u[8]; uint4 v; } pk;
#pragma unroll
    for (int j = 0; j < 8; ++j) pk.u[j] = f2bf(src[(size_t)j * 128]);
    size_t dst = OFF_W1 + ((size_t)n * 128 + c) * 256 + (size_t)(s << 4);
    *reinterpret_cast<uint4*>(ws + dst) = pk.v;
    return;
  }
  id -= T_W1;
  if (id < T_W2) {
    int w = id & 63, rest = id >> 6;
    int s = rest & 15, n = rest >> 4;
    const float* src = rw2 + (size_t)n * 8192 + (size_t)(s * 8) * 64 + w;
    union { unsigned short u[8]; uint4 v; } pk;
#pragma unroll
    for (int j = 0; j < 8; ++j) pk.u[j] = f2bf(src[(size_t)j * 64]);
    size_t dst = OFF_W2 + ((size_t)n * 64 + w) * 256 + (size_t)(s << 4);
    *reinterpret_cast<uint4*>(ws + dst) = pk.v;
    return;
  }
  id -= T_W2;
  if (id < T_F1) {
    int s = id & 15, o = id >> 4;
    const float* src = fc1w + (size_t)o * 128 + s * 8;
    union { unsigned short u[8]; uint4 v; } pk;
#pragma unroll
    for (int j = 0; j < 8; ++j) pk.u[j] = f2bf(src[j]);
    *reinterpret_cast<uint4*>(ws + OFF_F1 + (size_t)o * 256 + ((s ^ (o & 7)) << 4)) = pk.v;
    return;
  }
  id -= T_F1;
  if (id < T_F2) {
    int s = id & 15, o = id >> 4;
    const float* src = fc2w + (size_t)o * 128 + s * 8;
    union { unsigned short u[8]; uint4 v; } pk;
#pragma unroll
    for (int j = 0; j < 8; ++j) pk.u[j] = f2bf(src[j]);
    *reinterpret_cast<uint4*>(ws + OFF_F2 + (size_t)o * 256 + ((s ^ (o & 7)) << 4)) = pk.v;
  }
}

// ---------------- recon v4: weights in registers, 8x 64-row b-subtiles, dbuf SE pipeline ----------------
// GEMM1': C1t[h_out][b] = W1t . SE^T   (A = W1 frags in VGPR, B = SE tile in LDS)
// GEMM2': C2t[w][b]     = W2t . hn^T   (A = W2 frags in VGPR, B = hn tile in LDS)
// grid = (n, btg) so linear id % 8 == n % 8 -> same-n blocks share an XCD (weights L2-resident).
// tmp output: bf16 [b][n][w] stashed in the upper half of each b's 32KB out3 slot.
__global__ __launch_bounds__(256, 2) void recon_kernel(const float* __restrict__ se,
                                                       const float* __restrict__ rb1,
                                                       const float* __restrict__ rb2,
                                                       const unsigned char* __restrict__ ws,
                                                       float* __restrict__ out3) {
  __shared__ unsigned char sSE[2][16384];  // SE 64-row tiles (swizzled rows b, 256B)
  __shared__ unsigned char sHN[16384];     // hn 64-row tile  (swizzled rows b, 256B)

  const int tid = threadIdx.x;
  const int n = blockIdx.x;    // 0..127 node
  const int btg = blockIdx.y;  // 0..7  -> 512 b-rows each
  const int b0 = btg * 512;

  const int wave = tid >> 6, lane = tid & 63;
  const int wm = wave >> 1, wq = wave & 1;  // wm: out-row half, wq: b half (32 each)
  const int lr = lane & 15, lk = lane >> 4;

  // A-fragments of W1 (64 rows this wave-half) and W2 (32 rows): loop-invariant -> VGPRs.
  const unsigned char* w1b = ws + OFF_W1 + (size_t)n * 32768;
  const unsigned char* w2b = ws + OFF_W2 + (size_t)n * 16384;
  bf16x8 w1f[4][4], w2f[2][4];
#pragma unroll
  for (int m = 0; m < 4; ++m)
#pragma unroll
    for (int kk = 0; kk < 4; ++kk)
      w1f[m][kk] = gfrag_ld(w1b, wm * 64 + m * 16 + lr, kk * 4 + lk);
#pragma unroll
  for (int m = 0; m < 2; ++m)
#pragma unroll
    for (int kk = 0; kk < 4; ++kk)
      w2f[m][kk] = gfrag_ld(w2b, wm * 32 + m * 16 + lr, kk * 4 + lk);

  // biases (constant per lane across all tiles)
  float bias1[4][4], bias2[2][4];
#pragma unroll
  for (int m = 0; m < 4; ++m)
#pragma unroll
    for (int j = 0; j < 4; ++j) bias1[m][j] = rb1[(size_t)n * 128 + wm * 64 + m * 16 + lk * 4 + j];
#pragma unroll
  for (int m = 0; m < 2; ++m)
#pragma unroll
    for (int j = 0; j < 4; ++j) bias2[m][j] = rb2[(size_t)n * 64 + wm * 32 + m * 16 + lk * 4 + j];

  // stage SE subtile 0
  stage_f32_tile(se + ((size_t)b0 * 128 + n) * 128, 128 * 128, sSE[0], tid, 64);
  unsigned short* outus = reinterpret_cast<unsigned short*>(out3);
  __syncthreads();

  float4 fra[4], frb[4];  // next-tile staging registers

  for (int t = 0; t < 8; ++t) {
    unsigned char* bufc = sSE[t & 1];
    unsigned char* bufn = sSE[(t + 1) & 1];

    // issue next tile's global loads early (hide HBM latency under G1/epi/G2)
    if (t < 7) {
      const float* sb = se + ((size_t)(b0 + (t + 1) * 64) * 128 + n) * 128;
#pragma unroll
      for (int k = 0; k < 4; ++k) {
        int c = tid + k * 256;
        int row = c >> 4, s = c & 15;
        const float* p = sb + (size_t)row * 16384 + s * 8;
        fra[k] = *reinterpret_cast<const float4*>(p);
        frb[k] = *reinterpret_cast<const float4*>(p + 4);
      }
    }

    // GEMM1': 128(h_out) x 64(b) x 128(k); wave owns 64 x 32
    f32x4 acc[4][2] = {};
#pragma unroll
    for (int kk = 0; kk < 4; ++kk) {
      const int slot = kk * 4 + lk;
      bf16x8 bv[2];
#pragma unroll
      for (int q = 0; q < 2; ++q) bv[q] = frag_ld(bufc, wq * 32 + q * 16 + lr, slot);
#pragma unroll
      for (int m = 0; m < 4; ++m)
#pragma unroll
        for (int q = 0; q < 2; ++q)
          acc[m][q] = __builtin_amdgcn_mfma_f32_16x16x32_bf16(w1f[m][kk], bv[q], acc[m][q], 0, 0, 0);
    }

    // epilogue1: hn[b][k] = relu(C1t[k][b] + rb1[k]) -> bf16 into sHN (no barrier needed:
    // sHN's last readers finished before the previous iteration's closing barrier)
    // lane: b = wq*32+q*16+lr, k = wm*64+m*16+lk*4+j  -> 8B write
#pragma unroll
    for (int m = 0; m < 4; ++m) {
      const int k0 = wm * 64 + m * 16 + lk * 4;
      const int s16 = k0 >> 3, half = (k0 >> 2) & 1;
#pragma unroll
      for (int q = 0; q < 2; ++q) {
        const int b = wq * 32 + q * 16 + lr;
        union { unsigned short u[4]; uint2 v; } pk;
#pragma unroll
        for (int j = 0; j < 4; ++j) {
          float v = acc[m][q][j] + bias1[m][j];
          v = v > 0.f ? v : 0.f;
          pk.u[j] = f2bf(v);
        }
        *reinterpret_cast<uint2*>(sHN + b * 256 + ((s16 ^ (b & 7)) << 4) + half * 8) = pk.v;
      }
    }
    __syncthreads();  // hn fully written

    // GEMM2': 64(w) x 64(b) x 128(k); wave owns 32 x 32
    f32x4 acc2[2][2] = {};
#pragma unroll
    for (int kk = 0; kk < 4; ++kk) {
      const int slot = kk * 4 + lk;
      bf16x8 bv[2];
#pragma unroll
      for (int q = 0; q < 2; ++q) bv[q] = frag_ld(sHN, wq * 32 + q * 16 + lr, slot);
#pragma unroll
      for (int m = 0; m < 2; ++m)
#pragma unroll
        for (int q = 0; q < 2; ++q)
          acc2[m][q] = __builtin_amdgcn_mfma_f32_16x16x32_bf16(w2f[m][kk], bv[q], acc2[m][q], 0, 0, 0);
    }

    // write prefetched SE(t+1) into the other SE buffer (overlapped with G2/stores;
    // bufn's last readers were G1 of iter t-1, before the previous closing barrier)
    if (t < 7) {
#pragma unroll
      for (int k = 0; k < 4; ++k) {
        int c = tid + k * 256;
        int row = c >> 4, s = c & 15;
        union { unsigned short u[8]; uint4 v; } pk;
#pragma unroll
        for (int j = 0; j < 4; ++j) pk.u[j] = f2bf(fra[k][j]);
#pragma unroll
        for (int j = 0; j < 4; ++j) pk.u[4 + j] = f2bf(frb[k][j]);
        *reinterpret_cast<uint4*>(bufn + row * 256 + ((s ^ (row & 7)) << 4)) = pk.v;
      }
    }

    // epilogue2: tmp[b][n][w] bf16 at float-offset 4096 of b's out3 slot
    const int bt0 = b0 + t * 64;
#pragma unroll
    for (int m = 0; m < 2; ++m) {
      const int w0 = wm * 32 + m * 16 + lk * 4;
#pragma unroll
      for (int q = 0; q < 2; ++q) {
        const int b = bt0 + wq * 32 + q * 16 + lr;
        union { unsigned short u[4]; uint2 v; } pk;
#pragma unroll
        for (int j = 0; j < 4; ++j) pk.u[j] = f2bf(acc2[m][q][j] + bias2[m][j]);
        *reinterpret_cast<uint2*>(outus + (size_t)b * 16384 + 8192 + n * 64 + w0) = pk.v;
      }
    }
    __syncthreads();  // SE(t+1) staged; sHN reads done before next epi1
  }
}

// ---------------- transpose: tmp bf16 [b][n][w] -> out3 fp32 [b][w][n], LDS-free ----------------
__global__ __launch_bounds__(256) void transpose_kernel(float* __restrict__ out3) {
  const int b = blockIdx.x, wave = threadIdx.x >> 6, lane = threadIdx.x & 63;
  const unsigned short* t = reinterpret_cast<const unsigned short*>(out3) + (size_t)b * 16384 + 8192;
  float* dst = out3 + (size_t)b * 8192;
  uint4 r[2][2];
#pragma unroll
  for (int half = 0; half < 2; ++half) {
    const int g = half * 4 + wave;
    r[half][0] = *reinterpret_cast<const uint4*>(t + lane * 64 + g * 8);
    r[half][1] = *reinterpret_cast<const uint4*>(t + (size_t)(lane + 64) * 64 + g * 8);
  }
  __syncthreads();  // all reads done before dst writes clobber the tmp region
#pragma unroll
  for (int half = 0; half < 2; ++half) {
    const int g = half * 4 + wave;
    union { uint4 v; unsigned short u[8]; } p0, p1;
    p0.v = r[half][0];
    p1.v = r[half][1];
#pragma unroll
    for (int j = 0; j < 8; ++j) {
      dst[(g * 8 + j) * 128 + lane] = bf2f(p0.u[j]);
      dst[(g * 8 + j) * 128 + lane + 64] = bf2f(p1.u[j]);
    }
  }
}

// ---------------- forecast stage 1: h = relu(emb @ fc1^T + b1) -> ws (bf16, tile-swizzled) ----------------
__global__ __launch_bounds__(256) void f1_kernel(const float* __restrict__ emb,
                                                 const float* __restrict__ fc1b,
                                                 const unsigned char* __restrict__ ws,
                                                 unsigned char* __restrict__ hsw) {
  __shared__ unsigned char sA[32768];
  __shared__ unsigned char sB[32768];
  const int tid = threadIdx.x;
  const int bt = blockIdx.x;
  const int b0 = bt * 128;
  {
    const uint4* wp = reinterpret_cast<const uint4*>(ws + OFF_F1);
    uint4* d = reinterpret_cast<uint4*>(sB);
    for (int c = tid; c < 2048; c += 256) d[c] = wp[c];
  }
  stage_f32_tile(emb + (size_t)b0 * 128, 128, sA, tid, 128);
  __syncthreads();

  const int wave = tid >> 6, lane = tid & 63;
  const int wm = wave >> 1, wn = wave & 1;
  const int lr = lane & 15, lk = lane >> 4;

  f32x4 acc[4][4] = {};
#pragma unroll
  for (int kk = 0; kk < 4; ++kk) {
    bf16x8 af[4], bfv[4];
#pragma unroll
    for (int m = 0; m < 4; ++m) af[m] = frag_ld(sA, wm * 64 + m * 16 + lr, kk * 4 + lk);
#pragma unroll
    for (int q = 0; q < 4; ++q) bfv[q] = frag_ld(sB, wn * 64 + q * 16 + lr, kk * 4 + lk);
#pragma unroll
    for (int m = 0; m < 4; ++m)
#pragma unroll
      for (int q = 0; q < 4; ++q)
        acc[m][q] = __builtin_amdgcn_mfma_f32_16x16x32_bf16(af[m], bfv[q], acc[m][q], 0, 0, 0);
  }

  unsigned char* tile = hsw + (size_t)bt * 32768;
#pragma unroll
  for (int q = 0; q < 4; ++q) {
    int c = wn * 64 + q * 16 + lr;
    float bias = fc1b[c];
#pragma unroll
    for (int m = 0; m < 4; ++m) {
#pragma unroll
      for (int j = 0; j < 4; ++j) {
        int r = wm * 64 + m * 16 + lk * 4 + j;
        float v = acc[m][q][j] + bias;
        v = v > 0.f ? v : 0.f;
        *reinterpret_cast<unsigned short*>(tile + r * 256 + ((c * 2) ^ ((r & 7) << 4))) = f2bf(v);
      }
    }
  }
}

// ---------------- forecast stage 2: forecast = h @ fc2^T + b2 ----------------
__global__ __launch_bounds__(256) void f2_kernel(const unsigned char* __restrict__ hsw,
                                                 const unsigned char* __restrict__ f2s,
                                                 const float* __restrict__ fc2b,
                                                 float* __restrict__ out2) {
  __shared__ unsigned char sA[32768];
  __shared__ unsigned char sB[32768];
  const int tid = threadIdx.x;
  const int bt = blockIdx.x;      // 0..31
  const int ch = blockIdx.y;      // 0..2 (chunks of 128 output cols)
  const int b0 = bt * 128;
  {
    const uint4* ap = reinterpret_cast<const uint4*>(hsw + (size_t)bt * 32768);
    uint4* da = reinterpret_cast<uint4*>(sA);
    for (int c = tid; c < 2048; c += 256) da[c] = ap[c];
    const uint4* bp = reinterpret_cast<const uint4*>(f2s + (size_t)ch * 32768);
    uint4* db = reinterpret_cast<uint4*>(sB);
    for (int c = tid; c < 2048; c += 256) db[c] = bp[c];
  }
  __syncthreads();

  const int wave = tid >> 6, lane = tid & 63;
  const int wm = wave >> 1, wn = wave & 1;
  const int lr = lane & 15, lk = lane >> 4;

  f32x4 acc[4][4] = {};
#pragma unroll
  for (int kk = 0; kk < 4; ++kk) {
    bf16x8 af[4], bfv[4];
#pragma unroll
    for (int m = 0; m < 4; ++m) af[m] = frag_ld(sA, wm * 64 + m * 16 + lr, kk * 4 + lk);
#pragma unroll
    for (int q = 0; q < 4; ++q) bfv[q] = frag_ld(sB, wn * 64 + q * 16 + lr, kk * 4 + lk);
#pragma unroll
    for (int m = 0; m < 4; ++m)
#pragma unroll
      for (int q = 0; q < 4; ++q)
        acc[m][q] = __builtin_amdgcn_mfma_f32_16x16x32_bf16(af[m], bfv[q], acc[m][q], 0, 0, 0);
  }

#pragma unroll
  for (int q = 0; q < 4; ++q) {
    int o = ch * 128 + wn * 64 + q * 16 + lr;
    float bias = fc2b[o];
#pragma unroll
    for (int m = 0; m < 4; ++m) {
#pragma unroll
      for (int j = 0; j < 4; ++j) {
        int r = wm * 64 + m * 16 + lk * 4 + j;
        out2[(size_t)(b0 + r) * 384 + o] = acc[m][q][j] + bias;
      }
    }
  }
}

extern "C" void kernel_launch(void* const* d_in, const int* in_sizes, int n_in,
                              void* d_out, int out_size, void* d_ws, size_t ws_size,
                              hipStream_t stream) {
  const float* emb  = (const float*)d_in[0];
  const float* se   = (const float*)d_in[1];
  const float* slog = (const float*)d_in[2];
  const float* fc1w = (const float*)d_in[3];
  const float* fc1b = (const float*)d_in[4];
  const float* fc2w = (const float*)d_in[5];
  const float* fc2b = (const float*)d_in[6];
  const float* rw1  = (const float*)d_in[7];
  const float* rb1  = (const float*)d_in[8];
  const float* rw2  = (const float*)d_in[9];
  const float* rb2  = (const float*)d_in[10];
  float* out = (float*)d_out;
  unsigned char* ws = (unsigned char*)d_ws;

  // output 0: passthrough logits (B*N fp32)
  hipMemcpyAsync(out, slog, (size_t)B_SZ * N_SZ * sizeof(float),
                 hipMemcpyDeviceToDevice, stream);

  // weight prep (bf16 convert + transpose into ws)
  prep_kernel<<<1568, 256, 0, stream>>>(rw1, rw2, fc1w, fc2w, ws);

  // forecast head
  f1_kernel<<<32, 256, 0, stream>>>(emb, fc1b, ws, ws + OFF_H);
  f2_kernel<<<dim3(32, 3), 256, 0, stream>>>(ws + OFF_H, ws + OFF_F2, fc2b,
                                             out + (size_t)B_SZ * N_SZ);

  // reconstruction heads (dominant): weights-in-reg pipelined recon -> bf16 tmp -> transpose
  float* out3 = out + (size_t)B_SZ * N_SZ + (size_t)B_SZ * 384;
  recon_kernel<<<dim3(128, 8), 256, 0, stream>>>(se, rb1, rb2, ws, out3);
  transpose_kernel<<<4096, 256, 0, stream>>>(out3);
}